// Round 4
// baseline (244.859 us; speedup 1.0000x reference)
//
#include <hip/hip_runtime.h>
#include <hip/hip_bf16.h>

// MultiHeadAttention: B=2, S=2048, D=1024, H=16, DK=64
// Round 12: flash_attn keeps R11's 8-wave 2D (qg,kg) split + FTILE, but the
// staging schedule becomes a 3-deep K/V pipeline with counted vmcnt (T3/T4):
// tile t+2 is DMA'd during phase t and drained at top of phase t+2 via
// "s_waitcnt vmcnt(2)" + raw s_barrier (never vmcnt(0) in steady state).
// Mask uint4s are prefetched one it2 (=2 phases) ahead into VGPRs so the
// compiler's mask-wait cannot force a DMA drain. Rationale: R9 (-1 phase of
// DMA distance) cost +490cyc/phase while two occupancy doublings (R9,R11)
// were flat -> the per-phase vmcnt(0) drain is the suspected clock-setter.
// LDS: K bufs 3x8K @0, V bufs 3x8K @24576, P @49152 (67584 B, 2 blocks/CU).
// prep/proj_qkv/gemm_out unchanged.
// Workspace: qb@0 kb@8 vb@16 Wcat@24(6M) Wob@30 mbits@32 qhd@33 khd@41
//            vtd@49 oc@57  (MiB offsets)

using bf16x8 = __attribute__((ext_vector_type(8))) short;
using f32x4  = __attribute__((ext_vector_type(4))) float;

constexpr int Bc = 2, Sc = 2048, Dc = 1024, Hc = 16, DKc = 64;
constexpr int Mc = Bc * Sc;  // 4096
#define QSCALE 0.18033688011112042f  // log2(e)/sqrt(DK), folded into Q proj

__device__ __forceinline__ void lds_load16(const void* g, void* l) {
  __builtin_amdgcn_global_load_lds(
      (const __attribute__((address_space(1))) unsigned int*)g,
      (__attribute__((address_space(3))) unsigned int*)l, 16, 0, 0);
}

#if __has_builtin(__builtin_amdgcn_exp2f)
__device__ __forceinline__ float exp2_fast(float x) { return __builtin_amdgcn_exp2f(x); }
#else
__device__ __forceinline__ float exp2_fast(float x) {
  float r;
  asm("v_exp_f32 %0, %1\n\ts_nop 0" : "=v"(r) : "v"(x));
  return r;
}
#endif

// truncating bf16x2 pack: [hi16(b) : hi16(a)] — one v_perm_b32
__device__ __forceinline__ unsigned pack_trunc(float a, float b) {
  return __builtin_amdgcn_perm(__float_as_uint(b), __float_as_uint(a), 0x07060302u);
}

// RNE pack (epilogues)
__device__ __forceinline__ unsigned pack2bf(float a, float b) {
  union { __hip_bfloat16 h; unsigned short s; } ua, ub;
  ua.h = __float2bfloat16(a);
  ub.h = __float2bfloat16(b);
  return (unsigned)ua.s | ((unsigned)ub.s << 16);
}

// ---------------- prep: fused casts + mask pack ----------------
__global__ void prep(const float* __restrict__ q, const float* __restrict__ k,
                     const float* __restrict__ v, const int* __restrict__ mask,
                     const float* __restrict__ Wq, const float* __restrict__ Wk,
                     const float* __restrict__ Wv, const float* __restrict__ Wo,
                     char* __restrict__ ws) {
  const size_t MB = 1024 * 1024;
  int blk = blockIdx.x;
  if (blk < 12288) {
    int which = blk >> 12;
    int i = (((blk & 4095) << 8) + threadIdx.x) * 4;
    const float* s = which == 0 ? q : (which == 1 ? k : v);
    __hip_bfloat16* d = (__hip_bfloat16*)(ws + (size_t)which * 8 * MB);
    float4 x = *(const float4*)&s[i];
    uint2 pk = {pack2bf(x.x, x.y), pack2bf(x.z, x.w)};
    *(uint2*)&d[i] = pk;
  } else if (blk < 16384) {
    int bb = blk - 12288;
    int which = bb >> 10;
    int i = (((bb & 1023) << 8) + threadIdx.x) * 4;
    const float* s = which == 0 ? Wq : (which == 1 ? Wk : (which == 2 ? Wv : Wo));
    __hip_bfloat16* d = which < 3 ? (__hip_bfloat16*)(ws + (24 + 2 * which) * MB)
                                  : (__hip_bfloat16*)(ws + 30 * MB);
    float4 x = *(const float4*)&s[i];
    uint2 pk = {pack2bf(x.x, x.y), pack2bf(x.z, x.w)};
    *(uint2*)&d[i] = pk;
  } else {
    int i = ((blk - 16384) << 8) + threadIdx.x;
    unsigned long long bal = __ballot(mask[i] != 0);
    if ((threadIdx.x & 63) == 0)
      ((unsigned long long*)(ws + 32 * MB))[i >> 6] = bal;
  }
}

// ---------------- fused QKV projection (BK=32 dbuf) ----------------
// A = Wcat (features), B = X (s). Q/K: mfma(A=W,B=X) -> C col=s,row=feat ->
// packed dk stores. V: mfma(A=X,B=W) -> C col=feat,row=s -> packed s stores
// into V^T [B,H,DK,S]. flat grid 768, XCD swizzle, 3 blocks/CU.
__global__ __launch_bounds__(256, 3) void proj_qkv(
    const __hip_bfloat16* __restrict__ qb, const __hip_bfloat16* __restrict__ kb,
    const __hip_bfloat16* __restrict__ vb, const __hip_bfloat16* __restrict__ Wcat,
    const float* __restrict__ bq, const float* __restrict__ bk,
    const float* __restrict__ bv, __hip_bfloat16* __restrict__ qhd,
    __hip_bfloat16* __restrict__ khd, __hip_bfloat16* __restrict__ vtd) {
  __shared__ __align__(16) __hip_bfloat16 As[2][128 * 32];  // W tiles, 8KB each
  __shared__ __align__(16) __hip_bfloat16 Bs[2][128 * 32];  // X tiles
  const int tid = threadIdx.x;
  const int f = blockIdx.x, g = f >> 3;
  const int m0 = ((f & 7) * 4 + g / 24) * 128;  // s block
  const int n0 = (g % 24) * 128;                // feature block (0..3072)
  const int which = n0 >> 10, nl0 = n0 & 1023;
  const __hip_bfloat16* X = which == 0 ? qb : (which == 1 ? kb : vb);
  const float* bias = which == 0 ? bq : (which == 1 ? bk : bv);
  const int w = tid >> 6, lane = tid & 63, ln = lane & 15, quad = lane >> 4;
  const int rl = w * 32 + (lane >> 2);
  const int sw8 = ((lane & 3) ^ ((lane >> 2) & 3)) * 8;
  const int aoff = (n0 + rl) * 1024 + sw8;
  const int boff = (m0 + rl) * 1024 + sw8;
  char* aDst = (char*)As + w * 2048 + lane * 16;
  char* bDst = (char*)Bs + w * 2048 + lane * 16;
  const int rkq = (quad ^ (ln & 3)) * 16;
  const int rA0 = ((w >> 1) * 64 + ln) * 64 + rkq;   // + i*1024
  const int rB0 = ((w & 1) * 64 + ln) * 64 + rkq;    // + j*1024
  f32x4 acc[4][4] = {};  // [i: feature 16-blk][j: s 16-blk]

#define PSTAGE(KO, BI)                                                        \
  {                                                                           \
    lds_load16(&Wcat[aoff + (KO)], aDst + (BI)*8192);                         \
    lds_load16(&Wcat[aoff + 16384 + (KO)], aDst + (BI)*8192 + 1024);          \
    lds_load16(&X[boff + (KO)], bDst + (BI)*8192);                            \
    lds_load16(&X[boff + 16384 + (KO)], bDst + (BI)*8192 + 1024);             \
  }

  PSTAGE(0, 0);
  if (which == 2) {
    for (int kb32 = 0; kb32 < 32; ++kb32) {
      const int bi = kb32 & 1;
      __syncthreads();
      if (kb32 < 31) PSTAGE((kb32 + 1) * 32, bi ^ 1);
      bf16x8 af[4], bf[4];
#pragma unroll
      for (int i = 0; i < 4; ++i)
        af[i] = *(bf16x8*)((char*)As + bi * 8192 + rA0 + i * 1024);
#pragma unroll
      for (int j = 0; j < 4; ++j)
        bf[j] = *(bf16x8*)((char*)Bs + bi * 8192 + rB0 + j * 1024);
#pragma unroll
      for (int i = 0; i < 4; ++i)
#pragma unroll
        for (int j = 0; j < 4; ++j)  // swapped: A=X -> C rows = s
          acc[i][j] = __builtin_amdgcn_mfma_f32_16x16x32_bf16(bf[j], af[i],
                                                              acc[i][j], 0, 0, 0);
    }
  } else {
    for (int kb32 = 0; kb32 < 32; ++kb32) {
      const int bi = kb32 & 1;
      __syncthreads();
      if (kb32 < 31) PSTAGE((kb32 + 1) * 32, bi ^ 1);
      bf16x8 af[4], bf[4];
#pragma unroll
      for (int i = 0; i < 4; ++i)
        af[i] = *(bf16x8*)((char*)As + bi * 8192 + rA0 + i * 1024);
#pragma unroll
      for (int j = 0; j < 4; ++j)
        bf[j] = *(bf16x8*)((char*)Bs + bi * 8192 + rB0 + j * 1024);
#pragma unroll
      for (int i = 0; i < 4; ++i)
#pragma unroll
        for (int j = 0; j < 4; ++j)  // A=W -> C rows = features
          acc[i][j] = __builtin_amdgcn_mfma_f32_16x16x32_bf16(af[i], bf[j],
                                                              acc[i][j], 0, 0, 0);
    }
  }

  const int wA = (w >> 1) * 64, wB = (w & 1) * 64;
  if (which == 2) {
#pragma unroll
    for (int i = 0; i < 4; ++i) {
      int nf = nl0 + wA + i * 16 + ln;
      int h = nf >> 6, dk = nf & 63;
      float bb = bias[nf];
#pragma unroll
      for (int j = 0; j < 4; ++j) {
        int sb = m0 + wB + j * 16 + quad * 4;
        int b = sb >> 11, s = sb & 2047;
        float vv[4] = {acc[i][j][0] + bb, acc[i][j][1] + bb,
                       acc[i][j][2] + bb, acc[i][j][3] + bb};
        uint2 pk = {pack2bf(vv[0], vv[1]), pack2bf(vv[2], vv[3])};
        *(uint2*)&vtd[(((size_t)(b * Hc + h) * DKc + dk) * Sc) + s] = pk;
      }
    }
  } else {
#pragma unroll
    for (int i = 0; i < 4; ++i) {
      int nfb = nl0 + wA + i * 16 + quad * 4;
      float4 b4 = *(const float4*)&bias[nfb];
      int h = nfb >> 6, dk0 = nfb & 63;
#pragma unroll
      for (int j = 0; j < 4; ++j) {
        int sg = m0 + wB + j * 16 + ln;
        int b = sg >> 11, s = sg & 2047;
        float vv[4] = {acc[i][j][0] + b4.x, acc[i][j][1] + b4.y,
                       acc[i][j][2] + b4.z, acc[i][j][3] + b4.w};
        if (which == 0) {
          uint2 pk = {pack2bf(vv[0] * QSCALE, vv[1] * QSCALE),
                      pack2bf(vv[2] * QSCALE, vv[3] * QSCALE)};
          *(uint2*)&qhd[(((size_t)(b * Hc + h) * Sc + s) * DKc) + dk0] = pk;
        } else {
          uint2 pk = {pack2bf(vv[0], vv[1]), pack2bf(vv[2], vv[3])};
          *(uint2*)&khd[(((size_t)(b * Hc + h) * Sc + s) * DKc) + dk0] = pk;
        }
      }
    }
  }
}

// ---------------- out projection (swapped): Y = oc @ Wo^T + bo ------------
__global__ __launch_bounds__(256, 2) void gemm_out(
    const __hip_bfloat16* __restrict__ X, const __hip_bfloat16* __restrict__ W,
    const float* __restrict__ bias, float* __restrict__ Y) {
  __shared__ __align__(16) __hip_bfloat16 As[2][64 * 64];   // Wo tile
  __shared__ __align__(16) __hip_bfloat16 Bs[2][128 * 64];  // oc tile
  const int tid = threadIdx.x;
  const int f = blockIdx.x, g = f >> 3;
  const int m0 = ((f & 7) * 4 + (g >> 4)) * 128;  // s block
  const int n0 = (g & 15) * 64;                    // feature block
  const int w = tid >> 6, lane = tid & 63, ln = lane & 15, quad = lane >> 4;
  const int wA = (w & 1) * 32, wB = (w >> 1) * 64;
  const int swz = ((lane & 7) ^ (lane >> 3)) * 8;
  const int rk0 = ln * 128 + ((quad ^ (ln & 7)) * 16);
  const int rk1 = ln * 128 + (((quad + 4) ^ (ln & 7)) * 16);
  const int aoff = (n0 + w * 16 + (lane >> 3)) * 1024 + swz;
  const int boff = (m0 + w * 32 + (lane >> 3)) * 1024 + swz;
  f32x4 acc[2][4] = {};

#define OSTAGE(KO, BI)                                                        \
  {                                                                           \
    _Pragma("unroll") for (int i = 0; i < 2; ++i)                             \
        lds_load16(&W[aoff + i * 8192 + (KO)],                                \
                   (char*)As[BI] + w * 2048 + lane * 16 + i * 1024);          \
    _Pragma("unroll") for (int i = 0; i < 4; ++i)                             \
        lds_load16(&X[boff + i * 8192 + (KO)],                                \
                   (char*)Bs[BI] + w * 4096 + lane * 16 + i * 1024);          \
  }

  OSTAGE(0, 0);
  for (int kb64 = 0; kb64 < 16; ++kb64) {
    const int bi = kb64 & 1;
    __syncthreads();
    if (kb64 + 1 < 16) OSTAGE((kb64 + 1) * 64, bi ^ 1);
    bf16x8 af[2][2], bf[4][2];
#pragma unroll
    for (int i = 0; i < 2; ++i) {
      af[i][0] = *(bf16x8*)((char*)As[bi] + wA * 128 + i * 2048 + rk0);
      af[i][1] = *(bf16x8*)((char*)As[bi] + wA * 128 + i * 2048 + rk1);
    }
#pragma unroll
    for (int j = 0; j < 4; ++j) {
      bf[j][0] = *(bf16x8*)((char*)Bs[bi] + wB * 128 + j * 2048 + rk0);
      bf[j][1] = *(bf16x8*)((char*)Bs[bi] + wB * 128 + j * 2048 + rk1);
    }
#pragma unroll
    for (int i = 0; i < 2; ++i)
#pragma unroll
      for (int j = 0; j < 4; ++j) {
        acc[i][j] = __builtin_amdgcn_mfma_f32_16x16x32_bf16(af[i][0], bf[j][0],
                                                            acc[i][j], 0, 0, 0);
        acc[i][j] = __builtin_amdgcn_mfma_f32_16x16x32_bf16(af[i][1], bf[j][1],
                                                            acc[i][j], 0, 0, 0);
      }
  }
#pragma unroll
  for (int i = 0; i < 2; ++i) {
    int nfb = n0 + wA + i * 16 + quad * 4;
    float4 b4 = *(const float4*)&bias[nfb];
#pragma unroll
    for (int j = 0; j < 4; ++j) {
      int sg = m0 + wB + j * 16 + ln;
      float4 st = {acc[i][j][0] + b4.x, acc[i][j][1] + b4.y,
                   acc[i][j][2] + b4.z, acc[i][j][3] + b4.w};
      *(float4*)&Y[(size_t)sg * Dc + nfb] = st;
    }
  }
}

// ---------------- flash attention (8-wave 2D, 3-deep counted-vmcnt) -------
__global__ __launch_bounds__(512, 4) void flash_attn(
    const __hip_bfloat16* __restrict__ qh, const __hip_bfloat16* __restrict__ kh,
    const __hip_bfloat16* __restrict__ vt, const uint4* __restrict__ mb4,
    __hip_bfloat16* __restrict__ oc) {
  __shared__ __align__(16) char L[67584];
  const int tid = threadIdx.x;
  const int f = blockIdx.x, g = f >> 3;
  const int bh = (f & 7) * 4 + (g >> 4);  // 0..31
  const int q0 = (g & 15) * 128;
  const int b = bh >> 4, h = bh & 15;
  const int w = tid >> 6, lane = tid & 63, ln = lane & 15, quad = lane >> 4;
  const int qg = w >> 1, kg = w & 1;
  const size_t base = (size_t)bh * Sc * DKc;
  const __hip_bfloat16* khb = kh + base;
  const __hip_bfloat16* vtb = vt + base;

  bf16x8 qf[2][2];
#pragma unroll
  for (int qt = 0; qt < 2; ++qt)
#pragma unroll
    for (int kc = 0; kc < 2; ++kc)
      qf[qt][kc] = *(const bf16x8*)&qh[base +
          (size_t)(q0 + qg * 32 + qt * 16 + ln) * 64 + kc * 32 + quad * 8];

  bf16x8 onesA;
#pragma unroll
  for (int i = 0; i < 8; ++i) onesA[i] = (short)0x3F80;  // bf16 1.0

  const int swz = ((lane & 7) ^ (lane >> 3)) * 8;
  const int rk0 = ln * 128 + ((quad ^ (ln & 7)) * 16);
  const int rk1 = ln * 128 + (((quad + 4) ^ (ln & 7)) * 16);
  const int rkv = ln * 128 + ((((kg << 2) + quad) ^ (ln & 7)) * 16);
  // P rows: [qg][qt*16+ln] stride 144; kg halves at byte kg*64; base 49152
  const int rPw = 49152 + qg * 4608 + ln * 144 + kg * 64 + quad * 8;
  const int rPb = 49152 + qg * 4608 + ln * 144 + kg * 64 + quad * 16;
  char* dmaL = L + w * 1024 + lane * 16;   // + bufoff (K) / +24576+bufoff (V)
  int koff = (w * 8 + (lane >> 3)) * 64 + swz;
  int voff = (w * 8 + (lane >> 3)) * Sc + swz;
  int midx0 = (q0 + qg * 32 + ln) * 16;
  int midx1 = midx0 + 256;
  const int sh0 = quad * 4, sh1 = quad * 4 + 16;

// issue one K + one V load for the next staged tile into buffer byte-off BOFF
#define KV_DMA(BOFF)                                                          \
  {                                                                           \
    lds_load16(khb + koff, dmaL + (BOFF));                                    \
    lds_load16(vtb + voff, dmaL + 24576 + (BOFF));                            \
    koff += 4096; voff += 64;                                                 \
  }

// counted-vmcnt barrier: own 2 newest loads (next tile) stay in flight
#define WB2()                                                                 \
  {                                                                           \
    asm volatile("s_waitcnt vmcnt(2)" ::: "memory");                          \
    __builtin_amdgcn_s_barrier();                                             \
  }
#define WB0()                                                                 \
  {                                                                           \
    asm volatile("s_waitcnt vmcnt(0)" ::: "memory");                          \
    __builtin_amdgcn_s_barrier();                                             \
  }

  f32x4 Oacc[4][2] = {};
  f32x4 lacc[2] = {};

  // E0/E1: 32-bit mask words (this tile, kg half) for qt=0 / qt=1 rows.
#define FTILE(COFF, E0, E1)                                                   \
  {                                                                           \
    bf16x8 kf[2][2];                                                          \
    _Pragma("unroll") for (int tl = 0; tl < 2; ++tl) {                        \
      kf[tl][0] = *(bf16x8*)(L + (COFF) + (kg * 2 + tl) * 2048 + rk0);        \
      kf[tl][1] = *(bf16x8*)(L + (COFF) + (kg * 2 + tl) * 2048 + rk1);        \
    }                                                                         \
    _Pragma("unroll") for (int qt = 0; qt < 2; ++qt) {                        \
      f32x4 s4[2];                                                            \
      __builtin_amdgcn_s_setprio(1);                                          \
      _Pragma("unroll") for (int tl = 0; tl < 2; ++tl) {                      \
        f32x4 z = {0.f, 0.f, 0.f, 0.f};                                       \
        z = __builtin_amdgcn_mfma_f32_16x16x32_bf16(kf[tl][0], qf[qt][0], z,  \
                                                    0, 0, 0);                 \
        s4[tl] = __builtin_amdgcn_mfma_f32_16x16x32_bf16(kf[tl][1],           \
                                                         qf[qt][1], z, 0, 0, 0); \
      }                                                                       \
      __builtin_amdgcn_s_setprio(0);                                          \
      unsigned word = qt ? (E1) : (E0);                                       \
      _Pragma("unroll") for (int tl = 0; tl < 2; ++tl) {                      \
        unsigned pre = word >> (tl ? sh1 : sh0);                              \
        float p[4];                                                           \
        _Pragma("unroll") for (int r = 0; r < 4; ++r) {                       \
          float e = exp2_fast(s4[tl][r]);                                     \
          p[r] = (pre & (1u << r)) ? e : 0.f;                                 \
        }                                                                     \
        uint2 pk = {pack_trunc(p[0], p[1]), pack_trunc(p[2], p[3])};          \
        *(uint2*)(L + rPw + qt * 2304 + tl * 32) = pk;                        \
      }                                                                       \
    }                                                                         \
    bf16x8 vf[4], pb[2];                                                      \
    _Pragma("unroll") for (int dt = 0; dt < 4; ++dt)                          \
        vf[dt] = *(bf16x8*)(L + 24576 + (COFF) + dt * 2048 + rkv);            \
    _Pragma("unroll") for (int qt = 0; qt < 2; ++qt)                          \
        pb[qt] = *(bf16x8*)(L + rPb + qt * 2304);                             \
    __builtin_amdgcn_s_setprio(1);                                            \
    _Pragma("unroll") for (int qt = 0; qt < 2; ++qt)                          \
        lacc[qt] = __builtin_amdgcn_mfma_f32_16x16x32_bf16(onesA, pb[qt],     \
                                                           lacc[qt], 0, 0, 0); \
    _Pragma("unroll") for (int dt = 0; dt < 4; ++dt)                          \
        _Pragma("unroll") for (int qt = 0; qt < 2; ++qt)                      \
            Oacc[dt][qt] = __builtin_amdgcn_mfma_f32_16x16x32_bf16(           \
                vf[dt], pb[qt], Oacc[dt][qt], 0, 0, 0);                       \
    __builtin_amdgcn_s_setprio(0);                                            \
  }

  // prologue: mask(it2=0), tiles 0 and 1 into bufs 0,1 (6 loads in flight)
  uint4 mqC0 = mb4[midx0], mqC1 = mb4[midx1];
  ++midx0; ++midx1;
  KV_DMA(0);
  KV_DMA(8192);
  int curoff = 0, preoff = 16384;

  for (int it2 = 0; it2 < 16; ++it2) {
    uint4 mqN0, mqN1;
    // even phase: tile t = 2*it2
    WB2();  // forces DMA(t) + mask(it2); leaves DMA(t+1) in flight
    if (it2 < 15) {
      mqN0 = mb4[midx0]; mqN1 = mb4[midx1];
      ++midx0; ++midx1;
      KV_DMA(preoff);  // tile t+2
      preoff = preoff == 16384 ? 0 : preoff + 8192;
    }
    FTILE(curoff, kg ? mqC0.y : mqC0.x, kg ? mqC1.y : mqC1.x);
    curoff = curoff == 16384 ? 0 : curoff + 8192;
    // odd phase: tile t+1
    if (it2 < 15) {
      WB2();           // forces DMA(t+1); leaves DMA(t+2)
      KV_DMA(preoff);  // tile t+3
      preoff = preoff == 16384 ? 0 : preoff + 8192;
    } else {
      WB0();           // final tile: full drain
    }
    FTILE(curoff, kg ? mqC0.w : mqC0.z, kg ? mqC1.w : mqC1.z);
    curoff = curoff == 16384 ? 0 : curoff + 8192;
    if (it2 < 15) { mqC0 = mqN0; mqC1 = mqN1; }
  }

  // ---- k-combine epilogue: kg=1 ships partials, kg=0 merges + writes ----
  __syncthreads();  // full drain; K/V buf region reusable as O-exchange
  if (kg) {
#pragma unroll
    for (int dt = 0; dt < 4; ++dt)
#pragma unroll
      for (int qt = 0; qt < 2; ++qt) {
        int slot = (dt * 4 + quad) ^ ln;
        *(f32x4*)(L + qg * 8192 + (qt * 16 + ln) * 256 + slot * 16) =
            Oacc[dt][qt];
      }
    if (quad == 0) {  // spare bytes 128..131 of each P row
      *(float*)(L + 49152 + qg * 4608 + ln * 144 + 128) = lacc[0][0];
      *(float*)(L + 49152 + qg * 4608 + 2304 + ln * 144 + 128) = lacc[1][0];
    }
  }
  __syncthreads();
  if (!kg) {
    float linv[2];
#pragma unroll
    for (int qt = 0; qt < 2; ++qt) {
      float lsum = lacc[qt][0] +
                   *(float*)(L + 49152 + qg * 4608 + qt * 2304 + ln * 144 + 128);
      linv[qt] = 1.f / fmaxf(lsum, 1e-30f);
    }
#pragma unroll
    for (int dt = 0; dt < 4; ++dt)
#pragma unroll
      for (int qt = 0; qt < 2; ++qt) {
        int slot = (dt * 4 + quad) ^ ln;
        f32x4 part =
            *(f32x4*)(L + qg * 8192 + (qt * 16 + ln) * 256 + slot * 16);
        f32x4 o = Oacc[dt][qt];
        o[0] += part[0]; o[1] += part[1]; o[2] += part[2]; o[3] += part[3];
        uint2 pk = {pack2bf(o[0] * linv[qt], o[1] * linv[qt]),
                    pack2bf(o[2] * linv[qt], o[3] * linv[qt])};
        *(uint2*)(L + rPw + qt * 2304 + dt * 32) = pk;  // kg=0: bytes 0..127
      }
    __builtin_amdgcn_s_waitcnt(0);
#pragma unroll
    for (int chunk = 0; chunk < 4; ++chunk) {
      int row = chunk * 8 + (lane >> 3);
      bf16x8 val =
          *(bf16x8*)(L + 49152 + qg * 4608 + row * 144 + (lane & 7) * 16);
      int s = q0 + qg * 32 + row;
      *(bf16x8*)&oc[(size_t)(b * Sc + s) * Dc + h * 64 + (lane & 7) * 8] = val;
    }
  }
#undef KV_DMA
#undef FTILE
#undef WB2
#undef WB0
}

extern "C" void kernel_launch(void* const* d_in, const int* in_sizes, int n_in,
                              void* d_out, int out_size, void* d_ws, size_t ws_size,
                              hipStream_t stream) {
  const float* q  = (const float*)d_in[0];
  const float* k  = (const float*)d_in[1];
  const float* v  = (const float*)d_in[2];
  const int* mask = (const int*)d_in[3];
  const float* Wq = (const float*)d_in[4];
  const float* bq = (const float*)d_in[5];
  const float* Wk = (const float*)d_in[6];
  const float* bk = (const float*)d_in[7];
  const float* Wv = (const float*)d_in[8];
  const float* bv = (const float*)d_in[9];
  const float* Wo = (const float*)d_in[10];
  const float* bo = (const float*)d_in[11];

  char* ws = (char*)d_ws;
  const size_t MB = 1024 * 1024;
  __hip_bfloat16* qb   = (__hip_bfloat16*)(ws + 0 * MB);
  __hip_bfloat16* kb   = (__hip_bfloat16*)(ws + 8 * MB);
  __hip_bfloat16* vb   = (__hip_bfloat16*)(ws + 16 * MB);
  __hip_bfloat16* Wcat = (__hip_bfloat16*)(ws + 24 * MB);  // Wq|Wk|Wv
  __hip_bfloat16* Wob  = (__hip_bfloat16*)(ws + 30 * MB);
  uint4*          mb4  = (uint4*)(ws + 32 * MB);
  __hip_bfloat16* qhd  = (__hip_bfloat16*)(ws + 33 * MB);
  __hip_bfloat16* khd  = (__hip_bfloat16*)(ws + 41 * MB);
  __hip_bfloat16* vtd  = (__hip_bfloat16*)(ws + 49 * MB);
  __hip_bfloat16* oc   = (__hip_bfloat16*)(ws + 57 * MB);

  prep<<<32768, 256, 0, stream>>>(q, k, v, mask, Wq, Wk, Wv, Wo, ws);
  proj_qkv<<<768, 256, 0, stream>>>(qb, kb, vb, Wcat, bq, bk, bv, qhd, khd, vtd);
  flash_attn<<<512, 512, 0, stream>>>(qhd, khd, vtd, mb4, oc);
  gemm_out<<<512, 256, 0, stream>>>(oc, Wob, bo, (float*)d_out);
}

// Round 5
// 243.791 us; speedup vs baseline: 1.0044x; 1.0044x over previous
//
#include <hip/hip_runtime.h>
#include <hip/hip_bf16.h>

// MultiHeadAttention: B=2, S=2048, D=1024, H=16, DK=64
// Round 13: flash_attn rewritten in the m214-class 32x32 structure:
//  - swapped QK^T mfma_32x32x16(A=K, B=Q) -> C[k][q], q = lane&31 -> each
//    lane holds P for ONE q-row fully in registers (no P LDS round-trip;
//    R12 analysis: P-write+pb-read was 64KB/CU/phase of the 49%-busy LDS pipe
//    plus an intra-wave serialization).
//  - softmax in-register: exp2 + mask cndmask on 16 C regs/subtile; P->bf16
//    B-fragments via T12: 8 v_cvt_pk_bf16_f32 + 4 v_permlane32_swap_b32 per
//    subtile (one swap yields two B-words).
//  - l-sum via ones-MFMA (lacc = mfma(1, P)) on the 26%-busy matrix pipe.
//  - PV: mfma_32x32x16(A=V^T, B=P) -> O[d][q] accumulated in 2x f32x16.
//  - K [64k][64d] and V^T [64d][64k] LDS tiles, XOR-swizzled slots via
//    pre-swizzled GLOBAL source addrs (m173), linear global_load_lds dest.
//  - R8-proven dbuf + __syncthreads schedule (R9/R12 variants measured flat).
//  4 waves x 32 q-rows, grid 512 x 256thr, LDS 32KB, launch_bounds(256,2).
// prep/proj_qkv/gemm_out unchanged.
// Workspace: qb@0 kb@8 vb@16 Wcat@24(6M) Wob@30 mbits@32 qhd@33 khd@41
//            vtd@49 oc@57  (MiB offsets)

using bf16x8 = __attribute__((ext_vector_type(8))) short;
using f32x4  = __attribute__((ext_vector_type(4))) float;
using f32x16 = __attribute__((ext_vector_type(16))) float;

constexpr int Bc = 2, Sc = 2048, Dc = 1024, Hc = 16, DKc = 64;
constexpr int Mc = Bc * Sc;  // 4096
#define QSCALE 0.18033688011112042f  // log2(e)/sqrt(DK), folded into Q proj

__device__ __forceinline__ void lds_load16(const void* g, void* l) {
  __builtin_amdgcn_global_load_lds(
      (const __attribute__((address_space(1))) unsigned int*)g,
      (__attribute__((address_space(3))) unsigned int*)l, 16, 0, 0);
}

#if __has_builtin(__builtin_amdgcn_exp2f)
__device__ __forceinline__ float exp2_fast(float x) { return __builtin_amdgcn_exp2f(x); }
#else
__device__ __forceinline__ float exp2_fast(float x) {
  float r;
  asm("v_exp_f32 %0, %1\n\ts_nop 0" : "=v"(r) : "v"(x));
  return r;
}
#endif

// pack two f32 to bf16x2 word (RNE) via HW cvt
__device__ __forceinline__ unsigned cvt_pk_bf16(float lo, float hi) {
  unsigned r;
  asm("v_cvt_pk_bf16_f32 %0, %1, %2" : "=v"(r) : "v"(lo), "v"(hi));
  return r;
}

// in-place half-swap: a' = [a.lo | b.lo(from lane-32)], b' = [a.hi | b.hi]
#define PSWAP(A, B) \
  asm volatile("v_permlane32_swap_b32 %0, %1" : "+v"(A), "+v"(B))

// RNE pack (epilogues)
__device__ __forceinline__ unsigned pack2bf(float a, float b) {
  union { __hip_bfloat16 h; unsigned short s; } ua, ub;
  ua.h = __float2bfloat16(a);
  ub.h = __float2bfloat16(b);
  return (unsigned)ua.s | ((unsigned)ub.s << 16);
}

// ---------------- prep: fused casts + mask pack ----------------
__global__ void prep(const float* __restrict__ q, const float* __restrict__ k,
                     const float* __restrict__ v, const int* __restrict__ mask,
                     const float* __restrict__ Wq, const float* __restrict__ Wk,
                     const float* __restrict__ Wv, const float* __restrict__ Wo,
                     char* __restrict__ ws) {
  const size_t MB = 1024 * 1024;
  int blk = blockIdx.x;
  if (blk < 12288) {
    int which = blk >> 12;
    int i = (((blk & 4095) << 8) + threadIdx.x) * 4;
    const float* s = which == 0 ? q : (which == 1 ? k : v);
    __hip_bfloat16* d = (__hip_bfloat16*)(ws + (size_t)which * 8 * MB);
    float4 x = *(const float4*)&s[i];
    uint2 pk = {pack2bf(x.x, x.y), pack2bf(x.z, x.w)};
    *(uint2*)&d[i] = pk;
  } else if (blk < 16384) {
    int bb = blk - 12288;
    int which = bb >> 10;
    int i = (((bb & 1023) << 8) + threadIdx.x) * 4;
    const float* s = which == 0 ? Wq : (which == 1 ? Wk : (which == 2 ? Wv : Wo));
    __hip_bfloat16* d = which < 3 ? (__hip_bfloat16*)(ws + (24 + 2 * which) * MB)
                                  : (__hip_bfloat16*)(ws + 30 * MB);
    float4 x = *(const float4*)&s[i];
    uint2 pk = {pack2bf(x.x, x.y), pack2bf(x.z, x.w)};
    *(uint2*)&d[i] = pk;
  } else {
    int i = ((blk - 16384) << 8) + threadIdx.x;
    unsigned long long bal = __ballot(mask[i] != 0);
    if ((threadIdx.x & 63) == 0)
      ((unsigned long long*)(ws + 32 * MB))[i >> 6] = bal;
  }
}

// ---------------- fused QKV projection (BK=32 dbuf) ----------------
__global__ __launch_bounds__(256, 3) void proj_qkv(
    const __hip_bfloat16* __restrict__ qb, const __hip_bfloat16* __restrict__ kb,
    const __hip_bfloat16* __restrict__ vb, const __hip_bfloat16* __restrict__ Wcat,
    const float* __restrict__ bq, const float* __restrict__ bk,
    const float* __restrict__ bv, __hip_bfloat16* __restrict__ qhd,
    __hip_bfloat16* __restrict__ khd, __hip_bfloat16* __restrict__ vtd) {
  __shared__ __align__(16) __hip_bfloat16 As[2][128 * 32];  // W tiles, 8KB each
  __shared__ __align__(16) __hip_bfloat16 Bs[2][128 * 32];  // X tiles
  const int tid = threadIdx.x;
  const int f = blockIdx.x, g = f >> 3;
  const int m0 = ((f & 7) * 4 + g / 24) * 128;  // s block
  const int n0 = (g % 24) * 128;                // feature block (0..3072)
  const int which = n0 >> 10, nl0 = n0 & 1023;
  const __hip_bfloat16* X = which == 0 ? qb : (which == 1 ? kb : vb);
  const float* bias = which == 0 ? bq : (which == 1 ? bk : bv);
  const int w = tid >> 6, lane = tid & 63, ln = lane & 15, quad = lane >> 4;
  const int rl = w * 32 + (lane >> 2);
  const int sw8 = ((lane & 3) ^ ((lane >> 2) & 3)) * 8;
  const int aoff = (n0 + rl) * 1024 + sw8;
  const int boff = (m0 + rl) * 1024 + sw8;
  char* aDst = (char*)As + w * 2048 + lane * 16;
  char* bDst = (char*)Bs + w * 2048 + lane * 16;
  const int rkq = (quad ^ (ln & 3)) * 16;
  const int rA0 = ((w >> 1) * 64 + ln) * 64 + rkq;   // + i*1024
  const int rB0 = ((w & 1) * 64 + ln) * 64 + rkq;    // + j*1024
  f32x4 acc[4][4] = {};  // [i: feature 16-blk][j: s 16-blk]

#define PSTAGE(KO, BI)                                                        \
  {                                                                           \
    lds_load16(&Wcat[aoff + (KO)], aDst + (BI)*8192);                         \
    lds_load16(&Wcat[aoff + 16384 + (KO)], aDst + (BI)*8192 + 1024);          \
    lds_load16(&X[boff + (KO)], bDst + (BI)*8192);                            \
    lds_load16(&X[boff + 16384 + (KO)], bDst + (BI)*8192 + 1024);             \
  }

  PSTAGE(0, 0);
  if (which == 2) {
    for (int kb32 = 0; kb32 < 32; ++kb32) {
      const int bi = kb32 & 1;
      __syncthreads();
      if (kb32 < 31) PSTAGE((kb32 + 1) * 32, bi ^ 1);
      bf16x8 af[4], bf[4];
#pragma unroll
      for (int i = 0; i < 4; ++i)
        af[i] = *(bf16x8*)((char*)As + bi * 8192 + rA0 + i * 1024);
#pragma unroll
      for (int j = 0; j < 4; ++j)
        bf[j] = *(bf16x8*)((char*)Bs + bi * 8192 + rB0 + j * 1024);
#pragma unroll
      for (int i = 0; i < 4; ++i)
#pragma unroll
        for (int j = 0; j < 4; ++j)  // swapped: A=X -> C rows = s
          acc[i][j] = __builtin_amdgcn_mfma_f32_16x16x32_bf16(bf[j], af[i],
                                                              acc[i][j], 0, 0, 0);
    }
  } else {
    for (int kb32 = 0; kb32 < 32; ++kb32) {
      const int bi = kb32 & 1;
      __syncthreads();
      if (kb32 < 31) PSTAGE((kb32 + 1) * 32, bi ^ 1);
      bf16x8 af[4], bf[4];
#pragma unroll
      for (int i = 0; i < 4; ++i)
        af[i] = *(bf16x8*)((char*)As + bi * 8192 + rA0 + i * 1024);
#pragma unroll
      for (int j = 0; j < 4; ++j)
        bf[j] = *(bf16x8*)((char*)Bs + bi * 8192 + rB0 + j * 1024);
#pragma unroll
      for (int i = 0; i < 4; ++i)
#pragma unroll
        for (int j = 0; j < 4; ++j)  // A=W -> C rows = features
          acc[i][j] = __builtin_amdgcn_mfma_f32_16x16x32_bf16(af[i], bf[j],
                                                              acc[i][j], 0, 0, 0);
    }
  }

  const int wA = (w >> 1) * 64, wB = (w & 1) * 64;
  if (which == 2) {
#pragma unroll
    for (int i = 0; i < 4; ++i) {
      int nf = nl0 + wA + i * 16 + ln;
      int h = nf >> 6, dk = nf & 63;
      float bb = bias[nf];
#pragma unroll
      for (int j = 0; j < 4; ++j) {
        int sb = m0 + wB + j * 16 + quad * 4;
        int b = sb >> 11, s = sb & 2047;
        float vv[4] = {acc[i][j][0] + bb, acc[i][j][1] + bb,
                       acc[i][j][2] + bb, acc[i][j][3] + bb};
        uint2 pk = {pack2bf(vv[0], vv[1]), pack2bf(vv[2], vv[3])};
        *(uint2*)&vtd[(((size_t)(b * Hc + h) * DKc + dk) * Sc) + s] = pk;
      }
    }
  } else {
#pragma unroll
    for (int i = 0; i < 4; ++i) {
      int nfb = nl0 + wA + i * 16 + quad * 4;
      float4 b4 = *(const float4*)&bias[nfb];
      int h = nfb >> 6, dk0 = nfb & 63;
#pragma unroll
      for (int j = 0; j < 4; ++j) {
        int sg = m0 + wB + j * 16 + ln;
        int b = sg >> 11, s = sg & 2047;
        float vv[4] = {acc[i][j][0] + b4.x, acc[i][j][1] + b4.y,
                       acc[i][j][2] + b4.z, acc[i][j][3] + b4.w};
        if (which == 0) {
          uint2 pk = {pack2bf(vv[0] * QSCALE, vv[1] * QSCALE),
                      pack2bf(vv[2] * QSCALE, vv[3] * QSCALE)};
          *(uint2*)&qhd[(((size_t)(b * Hc + h) * Sc + s) * DKc) + dk0] = pk;
        } else {
          uint2 pk = {pack2bf(vv[0], vv[1]), pack2bf(vv[2], vv[3])};
          *(uint2*)&khd[(((size_t)(b * Hc + h) * Sc + s) * DKc) + dk0] = pk;
        }
      }
    }
  }
}

// ---------------- out projection (swapped): Y = oc @ Wo^T + bo ------------
__global__ __launch_bounds__(256, 2) void gemm_out(
    const __hip_bfloat16* __restrict__ X, const __hip_bfloat16* __restrict__ W,
    const float* __restrict__ bias, float* __restrict__ Y) {
  __shared__ __align__(16) __hip_bfloat16 As[2][64 * 64];   // Wo tile
  __shared__ __align__(16) __hip_bfloat16 Bs[2][128 * 64];  // oc tile
  const int tid = threadIdx.x;
  const int f = blockIdx.x, g = f >> 3;
  const int m0 = ((f & 7) * 4 + (g >> 4)) * 128;  // s block
  const int n0 = (g & 15) * 64;                    // feature block
  const int w = tid >> 6, lane = tid & 63, ln = lane & 15, quad = lane >> 4;
  const int wA = (w & 1) * 32, wB = (w >> 1) * 64;
  const int swz = ((lane & 7) ^ (lane >> 3)) * 8;
  const int rk0 = ln * 128 + ((quad ^ (ln & 7)) * 16);
  const int rk1 = ln * 128 + (((quad + 4) ^ (ln & 7)) * 16);
  const int aoff = (n0 + w * 16 + (lane >> 3)) * 1024 + swz;
  const int boff = (m0 + w * 32 + (lane >> 3)) * 1024 + swz;
  f32x4 acc[2][4] = {};

#define OSTAGE(KO, BI)                                                        \
  {                                                                           \
    _Pragma("unroll") for (int i = 0; i < 2; ++i)                             \
        lds_load16(&W[aoff + i * 8192 + (KO)],                                \
                   (char*)As[BI] + w * 2048 + lane * 16 + i * 1024);          \
    _Pragma("unroll") for (int i = 0; i < 4; ++i)                             \
        lds_load16(&X[boff + i * 8192 + (KO)],                                \
                   (char*)Bs[BI] + w * 4096 + lane * 16 + i * 1024);          \
  }

  OSTAGE(0, 0);
  for (int kb64 = 0; kb64 < 16; ++kb64) {
    const int bi = kb64 & 1;
    __syncthreads();
    if (kb64 + 1 < 16) OSTAGE((kb64 + 1) * 64, bi ^ 1);
    bf16x8 af[2][2], bf[4][2];
#pragma unroll
    for (int i = 0; i < 2; ++i) {
      af[i][0] = *(bf16x8*)((char*)As[bi] + wA * 128 + i * 2048 + rk0);
      af[i][1] = *(bf16x8*)((char*)As[bi] + wA * 128 + i * 2048 + rk1);
    }
#pragma unroll
    for (int j = 0; j < 4; ++j) {
      bf[j][0] = *(bf16x8*)((char*)Bs[bi] + wB * 128 + j * 2048 + rk0);
      bf[j][1] = *(bf16x8*)((char*)Bs[bi] + wB * 128 + j * 2048 + rk1);
    }
#pragma unroll
    for (int i = 0; i < 2; ++i)
#pragma unroll
      for (int j = 0; j < 4; ++j) {
        acc[i][j] = __builtin_amdgcn_mfma_f32_16x16x32_bf16(af[i][0], bf[j][0],
                                                            acc[i][j], 0, 0, 0);
        acc[i][j] = __builtin_amdgcn_mfma_f32_16x16x32_bf16(af[i][1], bf[j][1],
                                                            acc[i][j], 0, 0, 0);
      }
  }
#pragma unroll
  for (int i = 0; i < 2; ++i) {
    int nfb = n0 + wA + i * 16 + quad * 4;
    float4 b4 = *(const float4*)&bias[nfb];
#pragma unroll
    for (int j = 0; j < 4; ++j) {
      int sg = m0 + wB + j * 16 + ln;
      float4 st = {acc[i][j][0] + b4.x, acc[i][j][1] + b4.y,
                   acc[i][j][2] + b4.z, acc[i][j][3] + b4.w};
      *(float4*)&Y[(size_t)sg * Dc + nfb] = st;
    }
  }
}

// ---------------- flash attention (32x32, in-register P) ------------------
__global__ __launch_bounds__(256, 2) void flash_attn(
    const __hip_bfloat16* __restrict__ qh, const __hip_bfloat16* __restrict__ kh,
    const __hip_bfloat16* __restrict__ vt, const uint2* __restrict__ mb2,
    __hip_bfloat16* __restrict__ oc) {
  __shared__ __align__(16) char L[32768];  // K bufs 2x8K @0, V^T bufs 2x8K @16384
  const int tid = threadIdx.x;
  const int f = blockIdx.x, g = f >> 3;
  const int bh = (f & 7) * 4 + (g >> 4);  // 0..31
  const int q0 = (g & 15) * 128;
  const int b = bh >> 4, h = bh & 15;
  const int w = tid >> 6, lane = tid & 63, l31 = lane & 31, hi = lane >> 5;
  const size_t base = (size_t)bh * Sc * DKc;
  const __hip_bfloat16* khb = kh + base;
  const __hip_bfloat16* vtb = vt + base;
  const int qglob = q0 + w * 32 + l31;

  // Q B-fragments: B[d = dt*16 + hi*8 + j][q = l31]
  bf16x8 qf[4];
#pragma unroll
  for (int dt = 0; dt < 4; ++dt)
    qf[dt] = *(const bf16x8*)&qh[base + (size_t)qglob * 64 + dt * 16 + hi * 8];

  bf16x8 onesA;
#pragma unroll
  for (int i = 0; i < 8; ++i) onesA[i] = (short)0x3F80;  // bf16 1.0

  // DMA: linear LDS dest, pre-swizzled global src (slot s' holds d/k-slot
  // s'^(row&7)). K tile [64k][64d]; V^T tile [64d][64k].
  const int trow = tid >> 3, tcol = tid & 7;
  const int kbase = trow * 64 + ((tcol ^ (trow & 7)) * 8);    // elements
  const int vbase = trow * 2048 + ((tcol ^ (trow & 7)) * 8);  // elements
  char* Ld = L + tid * 16;

  const int rowb = l31 * 128;
  const int xs = lane & 7;

  f32x16 Oacc0 = {}, Oacc1 = {}, lacc = {};

#define STAGE(BI, T)                                                          \
  {                                                                           \
    lds_load16(khb + kbase + (T)*4096,        Ld + (BI)*8192);                \
    lds_load16(khb + kbase + (T)*4096 + 2048, Ld + (BI)*8192 + 4096);         \
    lds_load16(vtb + vbase + (T)*64,          Ld + 16384 + (BI)*8192);        \
    lds_load16(vtb + vbase + (T)*64 + 65536,  Ld + 16384 + (BI)*8192 + 4096); \
  }

  // process one 32-k subtile: QK^T (4 mfma) -> masked exp2 -> cvt_pk+permlane
  // -> pb[2*SUB], pb[2*SUB+1] (B-frags for PV k16-tiles)
#define PROC_SUB(BOFF, SUB, MW)                                               \
  {                                                                           \
    bf16x8 kf0 = *(bf16x8*)(L + (BOFF) + (SUB)*4096 + rowb + (((0 + hi) ^ xs) * 16)); \
    bf16x8 kf1 = *(bf16x8*)(L + (BOFF) + (SUB)*4096 + rowb + (((2 + hi) ^ xs) * 16)); \
    bf16x8 kf2 = *(bf16x8*)(L + (BOFF) + (SUB)*4096 + rowb + (((4 + hi) ^ xs) * 16)); \
    bf16x8 kf3 = *(bf16x8*)(L + (BOFF) + (SUB)*4096 + rowb + (((6 + hi) ^ xs) * 16)); \
    f32x16 c = {};                                                            \
    __builtin_amdgcn_s_setprio(1);                                            \
    c = __builtin_amdgcn_mfma_f32_32x32x16_bf16(kf0, qf[0], c, 0, 0, 0);      \
    c = __builtin_amdgcn_mfma_f32_32x32x16_bf16(kf1, qf[1], c, 0, 0, 0);      \
    c = __builtin_amdgcn_mfma_f32_32x32x16_bf16(kf2, qf[2], c, 0, 0, 0);      \
    c = __builtin_amdgcn_mfma_f32_32x32x16_bf16(kf3, qf[3], c, 0, 0, 0);      \
    __builtin_amdgcn_s_setprio(0);                                            \
    unsigned shm = (MW) >> (hi * 4);                                          \
    float p[16];                                                              \
    _Pragma("unroll") for (int r = 0; r < 16; ++r) {                          \
      unsigned tg = shm >> (8 * (r >> 2));                                    \
      float e = exp2_fast(c[r]);                                              \
      p[r] = (tg & (1u << (r & 3))) ? e : 0.f;                                \
    }                                                                         \
    unsigned w0 = cvt_pk_bf16(p[0], p[1]),   w1 = cvt_pk_bf16(p[2], p[3]);    \
    unsigned w2 = cvt_pk_bf16(p[4], p[5]),   w3 = cvt_pk_bf16(p[6], p[7]);    \
    unsigned w4 = cvt_pk_bf16(p[8], p[9]),   w5 = cvt_pk_bf16(p[10], p[11]);  \
    unsigned w6 = cvt_pk_bf16(p[12], p[13]), w7 = cvt_pk_bf16(p[14], p[15]);  \
    PSWAP(w0, w2); PSWAP(w1, w3); PSWAP(w4, w6); PSWAP(w5, w7);               \
    { union { unsigned u[4]; bf16x8 v; } t;                                   \
      t.u[0] = w0; t.u[1] = w1; t.u[2] = w2; t.u[3] = w3;                     \
      pb[(SUB)*2] = t.v; }                                                    \
    { union { unsigned u[4]; bf16x8 v; } t;                                   \
      t.u[0] = w4; t.u[1] = w5; t.u[2] = w6; t.u[3] = w7;                     \
      pb[(SUB)*2 + 1] = t.v; }                                                \
  }

  const uint2* mrow = mb2 + (size_t)qglob * 32;
  uint2 mbC = mrow[0];
  STAGE(0, 0);

  for (int t = 0; t < 32; ++t) {
    __syncthreads();  // drains STAGE(t); all waves done reading buf t-1
    uint2 mbN = mbC;
    if (t < 31) {
      mbN = mrow[t + 1];
      STAGE((t + 1) & 1, t + 1);  // full-tile pipeline distance (R8 pattern)
    }
    const int boff = (t & 1) * 8192;

    bf16x8 pb[4];
    PROC_SUB(boff, 0, mbC.x);
    PROC_SUB(boff, 1, mbC.y);

    // PV + l: A = V^T frag [d = do*32+l31][k = kt*16+hi*8+j], B = pb[kt]
    __builtin_amdgcn_s_setprio(1);
#pragma unroll
    for (int kt = 0; kt < 4; ++kt) {
      lacc = __builtin_amdgcn_mfma_f32_32x32x16_bf16(onesA, pb[kt], lacc, 0, 0, 0);
      bf16x8 vf0 = *(bf16x8*)(L + 16384 + boff + rowb + (((kt * 2 + hi) ^ xs) * 16));
      bf16x8 vf1 = *(bf16x8*)(L + 16384 + boff + 4096 + rowb + (((kt * 2 + hi) ^ xs) * 16));
      Oacc0 = __builtin_amdgcn_mfma_f32_32x32x16_bf16(vf0, pb[kt], Oacc0, 0, 0, 0);
      Oacc1 = __builtin_amdgcn_mfma_f32_32x32x16_bf16(vf1, pb[kt], Oacc1, 0, 0, 0);
    }
    __builtin_amdgcn_s_setprio(0);
    mbC = mbN;
  }

  // ---- epilogue: all state in registers; direct packed stores ----
  float linv = 1.f / fmaxf(lacc[0], 1e-30f);
  const size_t obase = (size_t)(b * Sc + qglob) * Dc + h * 64;
#pragma unroll
  for (int gq = 0; gq < 4; ++gq) {
    int d0 = gq * 8 + hi * 4;
    uint2 pk0 = {pack2bf(Oacc0[4 * gq] * linv, Oacc0[4 * gq + 1] * linv),
                 pack2bf(Oacc0[4 * gq + 2] * linv, Oacc0[4 * gq + 3] * linv)};
    *(uint2*)&oc[obase + d0] = pk0;
    uint2 pk1 = {pack2bf(Oacc1[4 * gq] * linv, Oacc1[4 * gq + 1] * linv),
                 pack2bf(Oacc1[4 * gq + 2] * linv, Oacc1[4 * gq + 3] * linv)};
    *(uint2*)&oc[obase + 32 + d0] = pk1;
  }
#undef STAGE
#undef PROC_SUB
}

extern "C" void kernel_launch(void* const* d_in, const int* in_sizes, int n_in,
                              void* d_out, int out_size, void* d_ws, size_t ws_size,
                              hipStream_t stream) {
  const float* q  = (const float*)d_in[0];
  const float* k  = (const float*)d_in[1];
  const float* v  = (const float*)d_in[2];
  const int* mask = (const int*)d_in[3];
  const float* Wq = (const float*)d_in[4];
  const float* bq = (const float*)d_in[5];
  const float* Wk = (const float*)d_in[6];
  const float* bk = (const float*)d_in[7];
  const float* Wv = (const float*)d_in[8];
  const float* bv = (const float*)d_in[9];
  const float* Wo = (const float*)d_in[10];
  const float* bo = (const float*)d_in[11];

  char* ws = (char*)d_ws;
  const size_t MB = 1024 * 1024;
  __hip_bfloat16* qb   = (__hip_bfloat16*)(ws + 0 * MB);
  __hip_bfloat16* kb   = (__hip_bfloat16*)(ws + 8 * MB);
  __hip_bfloat16* vb   = (__hip_bfloat16*)(ws + 16 * MB);
  __hip_bfloat16* Wcat = (__hip_bfloat16*)(ws + 24 * MB);  // Wq|Wk|Wv
  __hip_bfloat16* Wob  = (__hip_bfloat16*)(ws + 30 * MB);
  uint2*          mb2  = (uint2*)(ws + 32 * MB);
  __hip_bfloat16* qhd  = (__hip_bfloat16*)(ws + 33 * MB);
  __hip_bfloat16* khd  = (__hip_bfloat16*)(ws + 41 * MB);
  __hip_bfloat16* vtd  = (__hip_bfloat16*)(ws + 49 * MB);
  __hip_bfloat16* oc   = (__hip_bfloat16*)(ws + 57 * MB);

  prep<<<32768, 256, 0, stream>>>(q, k, v, mask, Wq, Wk, Wv, Wo, ws);
  proj_qkv<<<768, 256, 0, stream>>>(qb, kb, vb, Wcat, bq, bk, bv, qhd, khd, vtd);
  flash_attn<<<512, 256, 0, stream>>>(qhd, khd, vtd, mb2, oc);
  gemm_out<<<512, 256, 0, stream>>>(oc, Wob, bo, (float*)d_out);
}